// Round 12
// baseline (248.329 us; speedup 1.0000x reference)
//
#include <hip/hip_runtime.h>
#include <hip/hip_bf16.h>
#include <math.h>

#define LEAKY 0.2f
#define BSHIFT 7            // 128 nodes per bucket
#define NBUCK_MAX 1024
#define BCAP 6144           // fixed capacity per bucket (mean 4224, sigma ~64)
#define CHUNK 4096          // edges per binB block (fits full sort in LDS)
#define CCAP 6656           // binC stage capacity (>= BCAP)
// dynamic LDS arena for phase2: max(binC 28160 B, gemm1 15360 B)
#define PHASE2_LDS 28160

typedef __attribute__((ext_vector_type(8))) short short8v;
typedef __attribute__((ext_vector_type(4))) float f32x4;

__device__ __forceinline__ unsigned pkbf(float a, float b) {
  __hip_bfloat162 t = __float22bfloat162_rn(make_float2(a, b));
  return *(unsigned*)&t;
}
__device__ __forceinline__ unsigned short f2bf(float f) {
  __hip_bfloat16 h = __float2bfloat16(f);
  return *(unsigned short*)&h;
}
__device__ __forceinline__ float bflo(unsigned u) { return __uint_as_float(u << 16); }
__device__ __forceinline__ float bfhi(unsigned u) { return __uint_as_float(u & 0xFFFF0000u); }

// ============ setup: w1t (bf16 transpose of W1) + bucket cursor init ========
__global__ __launch_bounds__(256) void setup_kernel(
    const float* __restrict__ W1, unsigned short* __restrict__ w1t,
    int* __restrict__ bucketCursor) {
  int t = blockIdx.x * 256 + threadIdx.x;
  if (t < 64 * 512) {
    int k = t & 511, c = t >> 9;
    w1t[(size_t)c * 512 + k] = f2bf(W1[(size_t)k * 64 + c]);
  }
  if (t < NBUCK_MAX) bucketCursor[t] = t * BCAP;
}

// ============ binB v2: single global read, in-LDS counting sort, =============
// ============ bucket-sorted (coalesced-run) flush to ebuf        =============
__global__ __launch_bounds__(256) void binB_kernel(
    const int* __restrict__ src, const int* __restrict__ dst,
    int* __restrict__ bucketCursor, unsigned* __restrict__ ebuf,
    int E, int Etot, int NBUCK) {
  __shared__ unsigned stage[CHUNK];           // 16 KB
  __shared__ unsigned short sbk[CHUNK];       // 8 KB
  __shared__ unsigned sorted[CHUNK];          // 16 KB
  __shared__ unsigned short sbk2[CHUNK];      // 8 KB
  __shared__ int bcnt[NBUCK_MAX];             // 4 KB (reused as sort cursor)
  __shared__ int bofs[NBUCK_MAX];             // 4 KB
  __shared__ int bdel[NBUCK_MAX];             // 4 KB
  __shared__ int wsum[256];                   // 1 KB
  const int t = threadIdx.x;
  const int c0 = blockIdx.x * CHUNK;
  const int cnt = min(CHUNK, Etot - c0);
  for (int i = t; i < NBUCK_MAX; i += 256) bcnt[i] = 0;
  __syncthreads();
  // pass 1: load chunk once, histogram buckets
  for (int i = t; i < cnt; i += 256) {
    int g = c0 + i;
    int s, d;
    if (g < E) { s = src[g]; d = dst[g]; } else { s = d = g - E; }
    stage[i] = (unsigned)s | ((unsigned)(d & 127) << 20);
    int b = d >> BSHIFT;
    sbk[i] = (unsigned short)b;
    atomicAdd(&bcnt[b], 1);
  }
  __syncthreads();
  // block-exclusive scan over 1024 buckets (4 contiguous per thread)
  {
    int b4 = t * 4;
    int e0 = bcnt[b4], e1 = bcnt[b4 + 1], e2 = bcnt[b4 + 2], e3 = bcnt[b4 + 3];
    int ssum = e0 + e1 + e2 + e3;
    wsum[t] = ssum;
    __syncthreads();
    for (int off = 1; off < 256; off <<= 1) {
      int u = (t >= off) ? wsum[t - off] : 0;
      __syncthreads();
      wsum[t] += u;
      __syncthreads();
    }
    int excl = wsum[t] - ssum;
    bofs[b4] = excl;
    bofs[b4 + 1] = excl + e0;
    bofs[b4 + 2] = excl + e0 + e1;
    bofs[b4 + 3] = excl + e0 + e1 + e2;
  }
  __syncthreads();
  // global reservation per touched bucket; bdel maps local pos -> global slot
  for (int i = t; i < NBUCK; i += 256) {
    int c = bcnt[i];
    int r = c ? atomicAdd(&bucketCursor[i], c) : 0;
    bdel[i] = r - bofs[i];
  }
  __syncthreads();
  for (int i = t; i < NBUCK_MAX; i += 256) bcnt[i] = 0;   // reuse as cursor
  __syncthreads();
  // pass 2: in-LDS counting sort
  for (int i = t; i < cnt; i += 256) {
    int b = sbk[i];
    int pos = bofs[b] + atomicAdd(&bcnt[b], 1);
    sorted[pos] = stage[i];
    sbk2[pos] = (unsigned short)b;
  }
  __syncthreads();
  // pass 3: flush in bucket order (consecutive lanes -> consecutive slots)
  for (int i = t; i < cnt; i += 256) {
    int b = sbk2[i];
    ebuf[bdel[b] + i] = sorted[i];
  }
}

// ============ binC body (dynamic LDS) ============
__device__ __forceinline__ void binC_body(
    char* smem, const unsigned* __restrict__ ebuf,
    const int* __restrict__ bucketCursor, int2* __restrict__ seg,
    int* __restrict__ esrc, int N, int b) {
  unsigned* stage = (unsigned*)smem;                 // CCAP u32 = 26624 B
  int* hist = (int*)(smem + CCAP * 4);               // 512 B
  int* sA   = hist + 128;                            // 512 B
  int* curs = sA + 128;                              // 512 B
  const int t = threadIdx.x;
  const int lo = b * BCAP;
  const int cnt = bucketCursor[b] - lo;
  const int base = b << BSHIFT;
  if (t < 128) hist[t] = 0;
  __syncthreads();
  for (int i = t; i < cnt; i += 256) {
    unsigned p = ebuf[lo + i];
    stage[i] = p;
    atomicAdd(&hist[p >> 20], 1);
  }
  __syncthreads();
  int v = 0;
  if (t < 128) { v = hist[t]; sA[t] = v; }
  __syncthreads();
  for (int off = 1; off < 128; off <<= 1) {
    int u = 0;
    if (t < 128 && t >= off) u = sA[t - off];
    __syncthreads();
    if (t < 128) sA[t] += u;
    __syncthreads();
  }
  if (t < 128) {
    int excl = sA[t] - v;
    curs[t] = excl;
    if (base + t < N) seg[base + t] = make_int2(lo + excl, v);
  }
  __syncthreads();
  for (int i = t; i < cnt; i += 256) {
    unsigned p = stage[i];
    int pos = atomicAdd(&curs[p >> 20], 1);
    esrc[lo + pos] = (int)(p & 0xFFFFFu);
  }
}

// ============ GEMM1 body (dynamic LDS, software-pipelined staging) ==========
__device__ __forceinline__ void gemm1_body(
    char* smem, const float* __restrict__ x,
    const unsigned short* __restrict__ w1t, unsigned short* __restrict__ h1b,
    int M, int blk) {
  typedef unsigned short AsRow[40];
  AsRow* AsU = (AsRow*)smem;                         // 128*40*2 = 10240 B
  AsRow* BtU = (AsRow*)(smem + 128 * 40 * 2);        // 64*40*2 = 5120 B
  const int tid = threadIdx.x;
  const int m0 = blk * 128;
  const int w = tid >> 6, lane = tid & 63;
  const int l15 = lane & 15, lhi = lane >> 4;

  f32x4 acc[2][4];
#pragma unroll
  for (int r = 0; r < 2; ++r)
#pragma unroll
    for (int t = 0; t < 4; ++t) acc[r][t] = (f32x4){0.f, 0.f, 0.f, 0.f};

  float4 pv[4];
  short8v pw;
  const int cB = tid >> 2, kbB = (tid & 3) * 8;

#pragma unroll
  for (int u = 0; u < 4; ++u) {
    int q = u * 256 + tid;
    int r = q >> 3, c4 = q & 7;
    int gm = m0 + r;
    pv[u] = (gm < M) ? *(const float4*)(x + (size_t)gm * 512 + c4 * 4)
                     : make_float4(0.f, 0.f, 0.f, 0.f);
  }
  pw = *(const short8v*)(w1t + (size_t)cB * 512 + kbB);

  for (int k0 = 0; k0 < 512; k0 += 32) {
#pragma unroll
    for (int u = 0; u < 4; ++u) {
      int q = u * 256 + tid;
      int r = q >> 3, c4 = q & 7;
      *(uint2*)&AsU[r][c4 * 4] =
          make_uint2(pkbf(pv[u].x, pv[u].y), pkbf(pv[u].z, pv[u].w));
    }
    *(short8v*)&BtU[cB][kbB] = pw;
    __syncthreads();

    if (k0 + 32 < 512) {
      int k1 = k0 + 32;
#pragma unroll
      for (int u = 0; u < 4; ++u) {
        int q = u * 256 + tid;
        int r = q >> 3, c4 = q & 7;
        int gm = m0 + r;
        pv[u] = (gm < M) ? *(const float4*)(x + (size_t)gm * 512 + k1 + c4 * 4)
                         : make_float4(0.f, 0.f, 0.f, 0.f);
      }
      pw = *(const short8v*)(w1t + (size_t)cB * 512 + k1 + kbB);
    }

    short8v a0 = *(const short8v*)&AsU[32 * w + l15][lhi * 8];
    short8v a1 = *(const short8v*)&AsU[32 * w + 16 + l15][lhi * 8];
#pragma unroll
    for (int t = 0; t < 4; ++t) {
      short8v b = *(const short8v*)&BtU[16 * t + l15][lhi * 8];
      acc[0][t] = __builtin_amdgcn_mfma_f32_16x16x32_bf16(a0, b, acc[0][t], 0, 0, 0);
      acc[1][t] = __builtin_amdgcn_mfma_f32_16x16x32_bf16(a1, b, acc[1][t], 0, 0, 0);
    }
    __syncthreads();
  }
#pragma unroll
  for (int rt = 0; rt < 2; ++rt) {
#pragma unroll
    for (int t = 0; t < 4; ++t) {
#pragma unroll
      for (int reg = 0; reg < 4; ++reg) {
        int gm = m0 + 32 * w + 16 * rt + 4 * lhi + reg;
        if (gm < M) h1b[(size_t)gm * 64 + 16 * t + l15] = f2bf(acc[rt][t][reg]);
      }
    }
  }
}

// ============ phase2: binC (blocks [0,NBUCK)) ∥ gemm1 (rest) ============
__global__ __launch_bounds__(256) void phase2_kernel(
    const unsigned* __restrict__ ebuf, const int* __restrict__ bucketCursor,
    int2* __restrict__ seg, int* __restrict__ esrc, int N, int NBUCK,
    const float* __restrict__ x, const unsigned short* __restrict__ w1t,
    unsigned short* __restrict__ h1b) {
  extern __shared__ __align__(16) char smem[];
  const int b = blockIdx.x;
  if (b < NBUCK) {
    binC_body(smem, ebuf, bucketCursor, seg, esrc, N, b);
  } else {
    gemm1_body(smem, x, w1t, h1b, N, b - NBUCK);
  }
}

// ============ layer-1 aggregate + fused GEMM2 (2-deep row pipeline) =========
__global__ __launch_bounds__(256) void agg1_kernel(
    const int2* __restrict__ seg, const int* __restrict__ esrc,
    const unsigned short* __restrict__ h1b, const float* __restrict__ att_src,
    const float* __restrict__ att_dst, const float* __restrict__ b1,
    const float* __restrict__ W2, unsigned short* __restrict__ g2b, int N) {
  __shared__ float Ws[1024];
  {
    float4 v = ((const float4*)W2)[threadIdx.x & 255];
    *(float4*)&Ws[(threadIdx.x & 255) * 4] = v;
  }
  __syncthreads();
  int wid = (blockIdx.x * 256 + threadIdx.x) >> 6;
  int lane = threadIdx.x & 63;
  if (wid >= N) return;
  const int n = wid;
  const int eo = lane >> 3, q = lane & 7;
  float as[8], ad[8];
  {
    float4 t0 = *(const float4*)(att_src + 8 * q);
    float4 t1 = *(const float4*)(att_src + 8 * q + 4);
    as[0] = t0.x; as[1] = t0.y; as[2] = t0.z; as[3] = t0.w;
    as[4] = t1.x; as[5] = t1.y; as[6] = t1.z; as[7] = t1.w;
    t0 = *(const float4*)(att_dst + 8 * q);
    t1 = *(const float4*)(att_dst + 8 * q + 4);
    ad[0] = t0.x; ad[1] = t0.y; ad[2] = t0.z; ad[3] = t0.w;
    ad[4] = t1.x; ad[5] = t1.y; ad[6] = t1.z; ad[7] = t1.w;
  }
  float adn;
  {
    uint4 hv = *(const uint4*)(h1b + (size_t)n * 64 + 8 * q);
    adn = bflo(hv.x) * ad[0] + bfhi(hv.x) * ad[1] + bflo(hv.y) * ad[2] +
          bfhi(hv.y) * ad[3] + bflo(hv.z) * ad[4] + bfhi(hv.z) * ad[5] +
          bflo(hv.w) * ad[6] + bfhi(hv.w) * ad[7];
  }
  const int2 sg = seg[n];
  const int s0 = sg.x, s1 = sg.x + sg.y;
  float acc[8] = {0.f, 0.f, 0.f, 0.f, 0.f, 0.f, 0.f, 0.f};
  float psum = 0.f;
  int i = s0 + eo;
  uint4 hv;
  if (i < s1) {
    int s = esrc[i];
    hv = *(const uint4*)(h1b + (size_t)s * 64 + 8 * q);
  }
  for (; i < s1; ) {
    const int i2 = i + 8;
    uint4 hv_n;
    if (i2 < s1) {
      int s2 = esrc[i2];
      hv_n = *(const uint4*)(h1b + (size_t)s2 * 64 + 8 * q);  // issues early
    }
    float g[8];
    g[0] = bflo(hv.x); g[1] = bfhi(hv.x); g[2] = bflo(hv.y); g[3] = bfhi(hv.y);
    g[4] = bflo(hv.z); g[5] = bfhi(hv.z); g[6] = bflo(hv.w); g[7] = bfhi(hv.w);
    float u = g[0] * as[0] + g[1] * as[1] + g[2] * as[2] + g[3] * as[3] +
              g[4] * as[4] + g[5] * as[5] + g[6] * as[6] + g[7] * as[7];
    float e = u + adn;
    e = e > 0.f ? e : LEAKY * e;
    float p = __expf(e);
#pragma unroll
    for (int j = 0; j < 8; ++j) acc[j] += p * g[j];
    psum += p;
    hv = hv_n;
    i = i2;
  }
#pragma unroll
  for (int off = 8; off <= 32; off <<= 1) {
#pragma unroll
    for (int j = 0; j < 8; ++j) acc[j] += __shfl_xor(acc[j], off);
    psum += __shfl_xor(psum, off);
  }
  // epilogue (all lanes): normalize + bias + ELU in fp32
  float inv = 1.0f / (psum + 1e-16f);
  float4 b0 = *(const float4*)(b1 + 8 * q);
  float4 b14 = *(const float4*)(b1 + 8 * q + 4);
  float bb[8] = {b0.x, b0.y, b0.z, b0.w, b14.x, b14.y, b14.z, b14.w};
  float o[8];
#pragma unroll
  for (int j = 0; j < 8; ++j) {
    float v = acc[j] * inv + bb[j];
    o[j] = v > 0.f ? v : expm1f(v);
  }
  // fused GEMM2: lane (eo,q) does channels c = 2eo, 2eo+1 over rows 8q..8q+7
  float p0 = 0.f, p1 = 0.f;
#pragma unroll
  for (int j = 0; j < 8; ++j) {
    float2 wv = *(const float2*)&Ws[(8 * q + j) * 16 + 2 * eo];
    p0 += o[j] * wv.x;
    p1 += o[j] * wv.y;
  }
  p0 += __shfl_xor(p0, 1); p0 += __shfl_xor(p0, 2); p0 += __shfl_xor(p0, 4);
  p1 += __shfl_xor(p1, 1); p1 += __shfl_xor(p1, 2); p1 += __shfl_xor(p1, 4);
  if (q == 0)
    *(unsigned*)&g2b[(size_t)n * 16 + 2 * eo] = pkbf(p0, p1);
}

// ============ layer-2 aggregate + log_softmax (2-deep row pipeline) =========
__global__ __launch_bounds__(256) void agg2_kernel(
    const int2* __restrict__ seg, const int* __restrict__ esrc,
    const unsigned short* __restrict__ g2b, const float* __restrict__ att_src,
    const float* __restrict__ att_dst, const float* __restrict__ b2,
    float* __restrict__ out, int N) {
  int wid = (blockIdx.x * 256 + threadIdx.x) >> 6;
  int lane = threadIdx.x & 63;
  if (wid >= N) return;
  const int n = wid;
  const int eo = lane >> 2, q = lane & 3;
  const float4 as4 = *(const float4*)(att_src + 4 * q);
  const float4 ad4 = *(const float4*)(att_dst + 4 * q);

  float adn;
  {
    uint2 gv = *(const uint2*)(g2b + (size_t)n * 16 + 4 * q);
    float un = bflo(gv.x) * ad4.x + bfhi(gv.x) * ad4.y +
               bflo(gv.y) * ad4.z + bfhi(gv.y) * ad4.w;
    un += __shfl_xor(un, 1);
    un += __shfl_xor(un, 2);
    adn = un;
  }

  const int2 sg = seg[n];
  const int s0 = sg.x, s1 = sg.x + sg.y;
  float a0 = 0.f, a1 = 0.f, a2 = 0.f, a3 = 0.f, psum = 0.f;
  int i = s0 + eo;
  uint2 gv;
  if (i < s1) {
    int s = esrc[i];
    gv = *(const uint2*)(g2b + (size_t)s * 16 + 4 * q);
  }
  for (; i < s1; ) {
    const int i2 = i + 16;
    uint2 gv_n;
    if (i2 < s1) {
      int s2 = esrc[i2];
      gv_n = *(const uint2*)(g2b + (size_t)s2 * 16 + 4 * q);
    }
    float g0 = bflo(gv.x), g1 = bfhi(gv.x), g2v = bflo(gv.y), g3 = bfhi(gv.y);
    float u = g0 * as4.x + g1 * as4.y + g2v * as4.z + g3 * as4.w;
    u += __shfl_xor(u, 1);
    u += __shfl_xor(u, 2);
    float e = u + adn;
    e = e > 0.f ? e : LEAKY * e;
    float p = __expf(e);
    a0 += p * g0; a1 += p * g1; a2 += p * g2v; a3 += p * g3;
    psum += p;
    gv = gv_n;
    i = i2;
  }
#pragma unroll
  for (int off = 4; off <= 32; off <<= 1) {
    a0 += __shfl_xor(a0, off);
    a1 += __shfl_xor(a1, off);
    a2 += __shfl_xor(a2, off);
    a3 += __shfl_xor(a3, off);
    psum += __shfl_xor(psum, off);
  }

  float inv = 1.0f / (psum + 1e-16f);
  float z0 = a0 * inv + b2[4 * q + 0];
  float z1 = a1 * inv + b2[4 * q + 1];
  float z2 = a2 * inv + b2[4 * q + 2];
  float z3 = a3 * inv + b2[4 * q + 3];
  float mx = fmaxf(fmaxf(z0, z1), fmaxf(z2, z3));
  mx = fmaxf(mx, __shfl_xor(mx, 1));
  mx = fmaxf(mx, __shfl_xor(mx, 2));
  float ex = __expf(z0 - mx) + __expf(z1 - mx) + __expf(z2 - mx) + __expf(z3 - mx);
  ex += __shfl_xor(ex, 1);
  ex += __shfl_xor(ex, 2);
  float lse = mx + logf(ex);
  if (eo == 0)
    *(float4*)(out + (size_t)n * 16 + 4 * q) =
        make_float4(z0 - lse, z1 - lse, z2 - lse, z3 - lse);
}

extern "C" void kernel_launch(void* const* d_in, const int* in_sizes, int n_in,
                              void* d_out, int out_size, void* d_ws, size_t ws_size,
                              hipStream_t stream) {
  const float* x        = (const float*)d_in[0];
  const int*   ei       = (const int*)d_in[1];
  const float* W1       = (const float*)d_in[2];
  const float* att_src1 = (const float*)d_in[3];
  const float* att_dst1 = (const float*)d_in[4];
  const float* b1       = (const float*)d_in[5];
  const float* W2       = (const float*)d_in[6];
  const float* att_src2 = (const float*)d_in[7];
  const float* att_dst2 = (const float*)d_in[8];
  const float* b2       = (const float*)d_in[9];
  float* out = (float*)d_out;

  const int N = in_sizes[0] / 512;
  const int E = in_sizes[1] / 2;
  const int Etot = E + N;
  const int NBUCK = (N + 127) >> BSHIFT;       // 782
  const int GBLK = (N + 127) / 128;            // gemm1 blocks (782)

  char* base = (char*)d_ws;
  size_t off = 0;
  auto alloc = [&](size_t bytes) { void* p = base + off; off = (off + bytes + 15) & ~(size_t)15; return p; };
  unsigned short* h1b = (unsigned short*)alloc((size_t)N * 64 * 2);      // 12.8 MB
  unsigned short* g2b = (unsigned short*)alloc((size_t)N * 16 * 2);      // 3.2 MB
  int*      esrc  = (int*)alloc((size_t)NBUCK * BCAP * 4);               // 19.2 MB
  unsigned* ebuf  = (unsigned*)alloc((size_t)NBUCK * BCAP * 4);          // 19.2 MB
  int2*     seg   = (int2*)alloc((size_t)N * 8);                         // 0.8 MB
  int* bucketCursor = (int*)alloc(NBUCK_MAX * 4);
  unsigned short* w1t = (unsigned short*)alloc(64 * 512 * 2);

  const int* srcI = ei;
  const int* dstI = ei + E;

  // ---- setup + binB ----
  setup_kernel<<<128, 256, 0, stream>>>(W1, w1t, bucketCursor);
  binB_kernel<<<(Etot + CHUNK - 1) / CHUNK, 256, 0, stream>>>(
      srcI, dstI, bucketCursor, ebuf, E, Etot, NBUCK);

  // ---- phase2: binC (CSR finalize) overlapped with gemm1 (MFMA) ----
  phase2_kernel<<<NBUCK + GBLK, 256, PHASE2_LDS, stream>>>(
      ebuf, bucketCursor, seg, esrc, N, NBUCK, x, w1t, h1b);

  // ---- layer 1 (agg1 fuses GEMM2 epilogue) ----
  agg1_kernel<<<(N * 64 + 255) / 256, 256, 0, stream>>>(
      seg, esrc, h1b, att_src1, att_dst1, b1, W2, g2b, N);

  // ---- layer 2 ----
  agg2_kernel<<<(N * 64 + 255) / 256, 256, 0, stream>>>(
      seg, esrc, g2b, att_src2, att_dst2, b2, out, N);
}

// Round 13
// 243.605 us; speedup vs baseline: 1.0194x; 1.0194x over previous
//
#include <hip/hip_runtime.h>
#include <hip/hip_bf16.h>
#include <math.h>

#define LEAKY 0.2f
#define BSHIFT 7            // 128 nodes per bucket
#define NBUCK_MAX 1024
#define BCAP 6144           // fixed capacity per bucket (mean 4224, sigma ~64)
#define CHUNK 8192          // edges per binB block (stage-and-scatter: measured best)
#define CCAP 6656           // binC stage capacity (>= BCAP)
// dynamic LDS arena for phase2: max(binC 28160 B, gemm1 15360 B)
#define PHASE2_LDS 28160

typedef __attribute__((ext_vector_type(8))) short short8v;
typedef __attribute__((ext_vector_type(4))) float f32x4;

__device__ __forceinline__ unsigned pkbf(float a, float b) {
  __hip_bfloat162 t = __float22bfloat162_rn(make_float2(a, b));
  return *(unsigned*)&t;
}
__device__ __forceinline__ unsigned short f2bf(float f) {
  __hip_bfloat16 h = __float2bfloat16(f);
  return *(unsigned short*)&h;
}
__device__ __forceinline__ float bflo(unsigned u) { return __uint_as_float(u << 16); }
__device__ __forceinline__ float bfhi(unsigned u) { return __uint_as_float(u & 0xFFFF0000u); }

// ============ setup: w1t (bf16 transpose of W1) + bucket cursor init ========
__global__ __launch_bounds__(256) void setup_kernel(
    const float* __restrict__ W1, unsigned short* __restrict__ w1t,
    int* __restrict__ bucketCursor) {
  int t = blockIdx.x * 256 + threadIdx.x;
  if (t < 64 * 512) {
    int k = t & 511, c = t >> 9;
    w1t[(size_t)c * 512 + k] = f2bf(W1[(size_t)k * 64 + c]);
  }
  if (t < NBUCK_MAX) bucketCursor[t] = t * BCAP;
}

// ============ binB: stage chunk in LDS, reserve per bucket, scatter ==========
// (measured optimum across 3 variants; do not replace with counting sort)
__global__ __launch_bounds__(256) void binB_kernel(
    const int* __restrict__ src, const int* __restrict__ dst,
    int* __restrict__ bucketCursor, unsigned* __restrict__ ebuf,
    int E, int Etot, int NBUCK) {
  __shared__ unsigned stage[CHUNK];          // 32 KB
  __shared__ unsigned short sbk[CHUNK];      // 16 KB
  __shared__ int bcnt[NBUCK_MAX];
  __shared__ int bres[NBUCK_MAX];
  __shared__ int bcur[NBUCK_MAX];
  const int t = threadIdx.x;
  const int c0 = blockIdx.x * CHUNK;
  const int cnt = min(CHUNK, Etot - c0);
  for (int i = t; i < NBUCK_MAX; i += 256) bcnt[i] = 0;
  __syncthreads();
  for (int i = t; i < cnt; i += 256) {
    int g = c0 + i;
    int s, d;
    if (g < E) { s = src[g]; d = dst[g]; } else { s = d = g - E; }
    stage[i] = (unsigned)s | ((unsigned)(d & 127) << 20);
    sbk[i] = (unsigned short)(d >> BSHIFT);
    atomicAdd(&bcnt[d >> BSHIFT], 1);
  }
  __syncthreads();
  for (int i = t; i < NBUCK; i += 256) {
    int c = bcnt[i];
    bres[i] = c ? atomicAdd(&bucketCursor[i], c) : 0;   // absolute slot
    bcur[i] = 0;
  }
  __syncthreads();
  for (int i = t; i < cnt; i += 256) {
    int b = sbk[i];
    int slot = bres[b] + atomicAdd(&bcur[b], 1);
    ebuf[slot] = stage[i];
  }
}

// ============ binC body (dynamic LDS) ============
__device__ __forceinline__ void binC_body(
    char* smem, const unsigned* __restrict__ ebuf,
    const int* __restrict__ bucketCursor, int2* __restrict__ seg,
    int* __restrict__ esrc, int N, int b) {
  unsigned* stage = (unsigned*)smem;                 // CCAP u32 = 26624 B
  int* hist = (int*)(smem + CCAP * 4);               // 512 B
  int* sA   = hist + 128;                            // 512 B
  int* curs = sA + 128;                              // 512 B
  const int t = threadIdx.x;
  const int lo = b * BCAP;
  const int cnt = bucketCursor[b] - lo;
  const int base = b << BSHIFT;
  if (t < 128) hist[t] = 0;
  __syncthreads();
  for (int i = t; i < cnt; i += 256) {
    unsigned p = ebuf[lo + i];
    stage[i] = p;
    atomicAdd(&hist[p >> 20], 1);
  }
  __syncthreads();
  int v = 0;
  if (t < 128) { v = hist[t]; sA[t] = v; }
  __syncthreads();
  for (int off = 1; off < 128; off <<= 1) {
    int u = 0;
    if (t < 128 && t >= off) u = sA[t - off];
    __syncthreads();
    if (t < 128) sA[t] += u;
    __syncthreads();
  }
  if (t < 128) {
    int excl = sA[t] - v;
    curs[t] = excl;
    if (base + t < N) seg[base + t] = make_int2(lo + excl, v);
  }
  __syncthreads();
  for (int i = t; i < cnt; i += 256) {
    unsigned p = stage[i];
    int pos = atomicAdd(&curs[p >> 20], 1);
    esrc[lo + pos] = (int)(p & 0xFFFFFu);
  }
}

// ============ GEMM1 body (dynamic LDS, software-pipelined staging) ==========
__device__ __forceinline__ void gemm1_body(
    char* smem, const float* __restrict__ x,
    const unsigned short* __restrict__ w1t, unsigned short* __restrict__ h1b,
    int M, int blk) {
  typedef unsigned short AsRow[40];
  AsRow* AsU = (AsRow*)smem;                         // 128*40*2 = 10240 B
  AsRow* BtU = (AsRow*)(smem + 128 * 40 * 2);        // 64*40*2 = 5120 B
  const int tid = threadIdx.x;
  const int m0 = blk * 128;
  const int w = tid >> 6, lane = tid & 63;
  const int l15 = lane & 15, lhi = lane >> 4;

  f32x4 acc[2][4];
#pragma unroll
  for (int r = 0; r < 2; ++r)
#pragma unroll
    for (int t = 0; t < 4; ++t) acc[r][t] = (f32x4){0.f, 0.f, 0.f, 0.f};

  float4 pv[4];
  short8v pw;
  const int cB = tid >> 2, kbB = (tid & 3) * 8;

#pragma unroll
  for (int u = 0; u < 4; ++u) {
    int q = u * 256 + tid;
    int r = q >> 3, c4 = q & 7;
    int gm = m0 + r;
    pv[u] = (gm < M) ? *(const float4*)(x + (size_t)gm * 512 + c4 * 4)
                     : make_float4(0.f, 0.f, 0.f, 0.f);
  }
  pw = *(const short8v*)(w1t + (size_t)cB * 512 + kbB);

  for (int k0 = 0; k0 < 512; k0 += 32) {
#pragma unroll
    for (int u = 0; u < 4; ++u) {
      int q = u * 256 + tid;
      int r = q >> 3, c4 = q & 7;
      *(uint2*)&AsU[r][c4 * 4] =
          make_uint2(pkbf(pv[u].x, pv[u].y), pkbf(pv[u].z, pv[u].w));
    }
    *(short8v*)&BtU[cB][kbB] = pw;
    __syncthreads();

    if (k0 + 32 < 512) {
      int k1 = k0 + 32;
#pragma unroll
      for (int u = 0; u < 4; ++u) {
        int q = u * 256 + tid;
        int r = q >> 3, c4 = q & 7;
        int gm = m0 + r;
        pv[u] = (gm < M) ? *(const float4*)(x + (size_t)gm * 512 + k1 + c4 * 4)
                         : make_float4(0.f, 0.f, 0.f, 0.f);
      }
      pw = *(const short8v*)(w1t + (size_t)cB * 512 + k1 + kbB);
    }

    short8v a0 = *(const short8v*)&AsU[32 * w + l15][lhi * 8];
    short8v a1 = *(const short8v*)&AsU[32 * w + 16 + l15][lhi * 8];
#pragma unroll
    for (int t = 0; t < 4; ++t) {
      short8v b = *(const short8v*)&BtU[16 * t + l15][lhi * 8];
      acc[0][t] = __builtin_amdgcn_mfma_f32_16x16x32_bf16(a0, b, acc[0][t], 0, 0, 0);
      acc[1][t] = __builtin_amdgcn_mfma_f32_16x16x32_bf16(a1, b, acc[1][t], 0, 0, 0);
    }
    __syncthreads();
  }
#pragma unroll
  for (int rt = 0; rt < 2; ++rt) {
#pragma unroll
    for (int t = 0; t < 4; ++t) {
#pragma unroll
      for (int reg = 0; reg < 4; ++reg) {
        int gm = m0 + 32 * w + 16 * rt + 4 * lhi + reg;
        if (gm < M) h1b[(size_t)gm * 64 + 16 * t + l15] = f2bf(acc[rt][t][reg]);
      }
    }
  }
}

// ============ phase2: binC (blocks [0,NBUCK)) ∥ gemm1 (rest) ============
__global__ __launch_bounds__(256) void phase2_kernel(
    const unsigned* __restrict__ ebuf, const int* __restrict__ bucketCursor,
    int2* __restrict__ seg, int* __restrict__ esrc, int N, int NBUCK,
    const float* __restrict__ x, const unsigned short* __restrict__ w1t,
    unsigned short* __restrict__ h1b) {
  extern __shared__ __align__(16) char smem[];
  const int b = blockIdx.x;
  if (b < NBUCK) {
    binC_body(smem, ebuf, bucketCursor, seg, esrc, N, b);
  } else {
    gemm1_body(smem, x, w1t, h1b, N, b - NBUCK);
  }
}

// ============ layer-1 aggregate + fused GEMM2 (2-deep row pipeline) =========
__global__ __launch_bounds__(256) void agg1_kernel(
    const int2* __restrict__ seg, const int* __restrict__ esrc,
    const unsigned short* __restrict__ h1b, const float* __restrict__ att_src,
    const float* __restrict__ att_dst, const float* __restrict__ b1,
    const float* __restrict__ W2, unsigned short* __restrict__ g2b, int N) {
  __shared__ float Ws[1024];
  {
    float4 v = ((const float4*)W2)[threadIdx.x & 255];
    *(float4*)&Ws[(threadIdx.x & 255) * 4] = v;
  }
  __syncthreads();
  int wid = (blockIdx.x * 256 + threadIdx.x) >> 6;
  int lane = threadIdx.x & 63;
  if (wid >= N) return;
  const int n = wid;
  const int eo = lane >> 3, q = lane & 7;
  float as[8], ad[8];
  {
    float4 t0 = *(const float4*)(att_src + 8 * q);
    float4 t1 = *(const float4*)(att_src + 8 * q + 4);
    as[0] = t0.x; as[1] = t0.y; as[2] = t0.z; as[3] = t0.w;
    as[4] = t1.x; as[5] = t1.y; as[6] = t1.z; as[7] = t1.w;
    t0 = *(const float4*)(att_dst + 8 * q);
    t1 = *(const float4*)(att_dst + 8 * q + 4);
    ad[0] = t0.x; ad[1] = t0.y; ad[2] = t0.z; ad[3] = t0.w;
    ad[4] = t1.x; ad[5] = t1.y; ad[6] = t1.z; ad[7] = t1.w;
  }
  float adn;
  {
    uint4 hv = *(const uint4*)(h1b + (size_t)n * 64 + 8 * q);
    adn = bflo(hv.x) * ad[0] + bfhi(hv.x) * ad[1] + bflo(hv.y) * ad[2] +
          bfhi(hv.y) * ad[3] + bflo(hv.z) * ad[4] + bfhi(hv.z) * ad[5] +
          bflo(hv.w) * ad[6] + bfhi(hv.w) * ad[7];
  }
  const int2 sg = seg[n];
  const int s0 = sg.x, s1 = sg.x + sg.y;
  float acc[8] = {0.f, 0.f, 0.f, 0.f, 0.f, 0.f, 0.f, 0.f};
  float psum = 0.f;
  int i = s0 + eo;
  uint4 hv;
  if (i < s1) {
    int s = esrc[i];
    hv = *(const uint4*)(h1b + (size_t)s * 64 + 8 * q);
  }
  for (; i < s1; ) {
    const int i2 = i + 8;
    uint4 hv_n;
    if (i2 < s1) {
      int s2 = esrc[i2];
      hv_n = *(const uint4*)(h1b + (size_t)s2 * 64 + 8 * q);  // issues early
    }
    float g[8];
    g[0] = bflo(hv.x); g[1] = bfhi(hv.x); g[2] = bflo(hv.y); g[3] = bfhi(hv.y);
    g[4] = bflo(hv.z); g[5] = bfhi(hv.z); g[6] = bflo(hv.w); g[7] = bfhi(hv.w);
    float u = g[0] * as[0] + g[1] * as[1] + g[2] * as[2] + g[3] * as[3] +
              g[4] * as[4] + g[5] * as[5] + g[6] * as[6] + g[7] * as[7];
    float e = u + adn;
    e = e > 0.f ? e : LEAKY * e;
    float p = __expf(e);
#pragma unroll
    for (int j = 0; j < 8; ++j) acc[j] += p * g[j];
    psum += p;
    hv = hv_n;
    i = i2;
  }
#pragma unroll
  for (int off = 8; off <= 32; off <<= 1) {
#pragma unroll
    for (int j = 0; j < 8; ++j) acc[j] += __shfl_xor(acc[j], off);
    psum += __shfl_xor(psum, off);
  }
  // epilogue (all lanes): normalize + bias + ELU in fp32
  float inv = 1.0f / (psum + 1e-16f);
  float4 b0 = *(const float4*)(b1 + 8 * q);
  float4 b14 = *(const float4*)(b1 + 8 * q + 4);
  float bb[8] = {b0.x, b0.y, b0.z, b0.w, b14.x, b14.y, b14.z, b14.w};
  float o[8];
#pragma unroll
  for (int j = 0; j < 8; ++j) {
    float v = acc[j] * inv + bb[j];
    o[j] = v > 0.f ? v : expm1f(v);
  }
  // fused GEMM2: lane (eo,q) does channels c = 2eo, 2eo+1 over rows 8q..8q+7
  float p0 = 0.f, p1 = 0.f;
#pragma unroll
  for (int j = 0; j < 8; ++j) {
    float2 wv = *(const float2*)&Ws[(8 * q + j) * 16 + 2 * eo];
    p0 += o[j] * wv.x;
    p1 += o[j] * wv.y;
  }
  p0 += __shfl_xor(p0, 1); p0 += __shfl_xor(p0, 2); p0 += __shfl_xor(p0, 4);
  p1 += __shfl_xor(p1, 1); p1 += __shfl_xor(p1, 2); p1 += __shfl_xor(p1, 4);
  if (q == 0)
    *(unsigned*)&g2b[(size_t)n * 16 + 2 * eo] = pkbf(p0, p1);
}

// ============ layer-2 aggregate + log_softmax (2-deep row pipeline) =========
__global__ __launch_bounds__(256) void agg2_kernel(
    const int2* __restrict__ seg, const int* __restrict__ esrc,
    const unsigned short* __restrict__ g2b, const float* __restrict__ att_src,
    const float* __restrict__ att_dst, const float* __restrict__ b2,
    float* __restrict__ out, int N) {
  int wid = (blockIdx.x * 256 + threadIdx.x) >> 6;
  int lane = threadIdx.x & 63;
  if (wid >= N) return;
  const int n = wid;
  const int eo = lane >> 2, q = lane & 3;
  const float4 as4 = *(const float4*)(att_src + 4 * q);
  const float4 ad4 = *(const float4*)(att_dst + 4 * q);

  float adn;
  {
    uint2 gv = *(const uint2*)(g2b + (size_t)n * 16 + 4 * q);
    float un = bflo(gv.x) * ad4.x + bfhi(gv.x) * ad4.y +
               bflo(gv.y) * ad4.z + bfhi(gv.y) * ad4.w;
    un += __shfl_xor(un, 1);
    un += __shfl_xor(un, 2);
    adn = un;
  }

  const int2 sg = seg[n];
  const int s0 = sg.x, s1 = sg.x + sg.y;
  float a0 = 0.f, a1 = 0.f, a2 = 0.f, a3 = 0.f, psum = 0.f;
  int i = s0 + eo;
  uint2 gv;
  if (i < s1) {
    int s = esrc[i];
    gv = *(const uint2*)(g2b + (size_t)s * 16 + 4 * q);
  }
  for (; i < s1; ) {
    const int i2 = i + 16;
    uint2 gv_n;
    if (i2 < s1) {
      int s2 = esrc[i2];
      gv_n = *(const uint2*)(g2b + (size_t)s2 * 16 + 4 * q);
    }
    float g0 = bflo(gv.x), g1 = bfhi(gv.x), g2v = bflo(gv.y), g3 = bfhi(gv.y);
    float u = g0 * as4.x + g1 * as4.y + g2v * as4.z + g3 * as4.w;
    u += __shfl_xor(u, 1);
    u += __shfl_xor(u, 2);
    float e = u + adn;
    e = e > 0.f ? e : LEAKY * e;
    float p = __expf(e);
    a0 += p * g0; a1 += p * g1; a2 += p * g2v; a3 += p * g3;
    psum += p;
    gv = gv_n;
    i = i2;
  }
#pragma unroll
  for (int off = 4; off <= 32; off <<= 1) {
    a0 += __shfl_xor(a0, off);
    a1 += __shfl_xor(a1, off);
    a2 += __shfl_xor(a2, off);
    a3 += __shfl_xor(a3, off);
    psum += __shfl_xor(psum, off);
  }

  float inv = 1.0f / (psum + 1e-16f);
  float z0 = a0 * inv + b2[4 * q + 0];
  float z1 = a1 * inv + b2[4 * q + 1];
  float z2 = a2 * inv + b2[4 * q + 2];
  float z3 = a3 * inv + b2[4 * q + 3];
  float mx = fmaxf(fmaxf(z0, z1), fmaxf(z2, z3));
  mx = fmaxf(mx, __shfl_xor(mx, 1));
  mx = fmaxf(mx, __shfl_xor(mx, 2));
  float ex = __expf(z0 - mx) + __expf(z1 - mx) + __expf(z2 - mx) + __expf(z3 - mx);
  ex += __shfl_xor(ex, 1);
  ex += __shfl_xor(ex, 2);
  float lse = mx + logf(ex);
  if (eo == 0)
    *(float4*)(out + (size_t)n * 16 + 4 * q) =
        make_float4(z0 - lse, z1 - lse, z2 - lse, z3 - lse);
}

extern "C" void kernel_launch(void* const* d_in, const int* in_sizes, int n_in,
                              void* d_out, int out_size, void* d_ws, size_t ws_size,
                              hipStream_t stream) {
  const float* x        = (const float*)d_in[0];
  const int*   ei       = (const int*)d_in[1];
  const float* W1       = (const float*)d_in[2];
  const float* att_src1 = (const float*)d_in[3];
  const float* att_dst1 = (const float*)d_in[4];
  const float* b1       = (const float*)d_in[5];
  const float* W2       = (const float*)d_in[6];
  const float* att_src2 = (const float*)d_in[7];
  const float* att_dst2 = (const float*)d_in[8];
  const float* b2       = (const float*)d_in[9];
  float* out = (float*)d_out;

  const int N = in_sizes[0] / 512;
  const int E = in_sizes[1] / 2;
  const int Etot = E + N;
  const int NBUCK = (N + 127) >> BSHIFT;       // 782
  const int GBLK = (N + 127) / 128;            // gemm1 blocks (782)

  char* base = (char*)d_ws;
  size_t off = 0;
  auto alloc = [&](size_t bytes) { void* p = base + off; off = (off + bytes + 15) & ~(size_t)15; return p; };
  unsigned short* h1b = (unsigned short*)alloc((size_t)N * 64 * 2);      // 12.8 MB
  unsigned short* g2b = (unsigned short*)alloc((size_t)N * 16 * 2);      // 3.2 MB
  int*      esrc  = (int*)alloc((size_t)NBUCK * BCAP * 4);               // 19.2 MB
  unsigned* ebuf  = (unsigned*)alloc((size_t)NBUCK * BCAP * 4);          // 19.2 MB
  int2*     seg   = (int2*)alloc((size_t)N * 8);                         // 0.8 MB
  int* bucketCursor = (int*)alloc(NBUCK_MAX * 4);
  unsigned short* w1t = (unsigned short*)alloc(64 * 512 * 2);

  const int* srcI = ei;
  const int* dstI = ei + E;

  // ---- setup + binB ----
  setup_kernel<<<128, 256, 0, stream>>>(W1, w1t, bucketCursor);
  binB_kernel<<<(Etot + CHUNK - 1) / CHUNK, 256, 0, stream>>>(
      srcI, dstI, bucketCursor, ebuf, E, Etot, NBUCK);

  // ---- phase2: binC (CSR finalize) overlapped with gemm1 (MFMA) ----
  phase2_kernel<<<NBUCK + GBLK, 256, PHASE2_LDS, stream>>>(
      ebuf, bucketCursor, seg, esrc, N, NBUCK, x, w1t, h1b);

  // ---- layer 1 (agg1 fuses GEMM2 epilogue) ----
  agg1_kernel<<<(N * 64 + 255) / 256, 256, 0, stream>>>(
      seg, esrc, h1b, att_src1, att_dst1, b1, W2, g2b, N);

  // ---- layer 2 ----
  agg2_kernel<<<(N * 64 + 255) / 256, 256, 0, stream>>>(
      seg, esrc, g2b, att_src2, att_dst2, b2, out, N);
}